// Round 7
// baseline (320.457 us; speedup 1.0000x reference)
//
#include <hip/hip_runtime.h>
#include <hip/hip_bf16.h>

#define N_NODES 4096
#define N_EDGES 8192
#define NGRAPH  256
#define AFEAT   9
#define BFEAT   4
#define H       128
#define NL      3
#define KS      129              // k-slices including the e2_b bias slice
#define SPLITS  4
#define TILE_E  64
#define SLICE_SH    16384        // shorts per k-slice (chunked layout)
#define SLICE_BYTES 32768        // bytes per k-slice

typedef short short8 __attribute__((ext_vector_type(8)));
typedef float f32x4 __attribute__((ext_vector_type(4)));

// ---- bf16 helpers (RNE, finite inputs) ----
__device__ __forceinline__ short f2b(float f){
    union { float f; unsigned u; } c; c.f = f;
    unsigned r = c.u + 0x7FFFu + ((c.u >> 16) & 1u);
    return (short)(r >> 16);
}
__device__ __forceinline__ float gelu_exact(float x){
    return 0.5f * x * (1.0f + erff(x * 0.70710678118654752440f));
}

// ---------- K0: e2_w/e2_b -> bt[l][k] in fragment-chunk order ----------
// Element B_k[i][o] stored at short offset
// (((o>>4)*4 + (i>>5))*64 + ((i>>3)&3)*16 + (o&15))*8 + (i&7).
// For fixed (o-tile t, ic): a wave's B fragment is the contiguous aligned
// 1 KB line at byte off (t*4+ic)*1024 + lane*16 -> one perfectly-coalesced
// global_load_dwordx4 per (t,ic) straight into registers (no LDS round-trip).
__global__ void k_prep_b(const float* __restrict__ e2w, const float* __restrict__ e2b,
                         short* __restrict__ bt){
    __shared__ float ts[H][33];
    int b  = blockIdx.x;
    int o0 = (b & 3) * 32;
    int k  = (b >> 2) % KS;
    int l  = (b >> 2) / KS;
    const float* src = (k < H) ? (e2w + ((size_t)l * H + k) * (H * H))
                               : (e2b + (size_t)l * (H * H));
    for (int idx = threadIdx.x; idx < H * 32; idx += 256){
        int i = idx >> 5, op = idx & 31;
        ts[i][op] = src[i * H + o0 + op];
    }
    __syncthreads();
    short* dst = bt + (size_t)(l * KS + k) * SLICE_SH;
    for (int idx = threadIdx.x; idx < 32 * H; idx += 256){
        int j    = idx & 7;
        int quad = (idx >> 3) & 3;
        int op   = (idx >> 5) & 31;
        int ic   = idx >> 10;
        int i    = ic * 32 + quad * 8 + j;
        int o    = o0 + op;
        dst[((((o >> 4) * 4 + ic) * 64) + quad * 16 + (o & 15)) * 8 + j] = f2b(ts[i][op]);
    }
}

// ---------- K1: h0 = relu(x @ atom_w + atom_b) ----------
__global__ void k_atom(const float* __restrict__ x, const float* __restrict__ aw,
                       const float* __restrict__ ab, float* __restrict__ h,
                       short* __restrict__ hb){
    __shared__ float xs[AFEAT];
    int n = blockIdx.x, o = threadIdx.x;
    if (o < AFEAT) xs[o] = x[n * AFEAT + o];
    __syncthreads();
    float a = ab[o];
    #pragma unroll
    for (int f = 0; f < AFEAT; ++f) a += xs[f] * aw[f * H + o];
    a = fmaxf(a, 0.0f);
    h[(size_t)n * H + o]  = a;
    hb[(size_t)n * H + o] = f2b(a);
}

// ---------- K2: in-degree (int histogram) ----------
__global__ void k_deg(const int* __restrict__ ei, int* __restrict__ ideg){
    int e = blockIdx.x * 256 + threadIdx.x;
    if (e < N_EDGES) atomicAdd(&ideg[ei[N_EDGES + e]], 1);
}

// ---------- K2b: exclusive scan -> row_ptr + cursor (one block, once) ----------
__global__ void k_scan(const int* __restrict__ ideg, int* __restrict__ row_ptr,
                       int* __restrict__ cursor){
    __shared__ int part[256];
    int t = threadIdx.x;
    int base = t * 16;
    int loc[16]; int s = 0;
    #pragma unroll
    for (int i = 0; i < 16; ++i){ loc[i] = s; s += ideg[base + i]; }
    part[t] = s;
    __syncthreads();
    if (t == 0){
        int run = 0;
        for (int i = 0; i < 256; ++i){ int v = part[i]; part[i] = run; run += v; }
        row_ptr[N_NODES] = run;
    }
    __syncthreads();
    int off = part[t];
    #pragma unroll
    for (int i = 0; i < 16; ++i){
        row_ptr[base + i] = off + loc[i];
        cursor[base + i]  = off + loc[i];
    }
}

// ---------- K2c: fill CSR edge-id list (once) ----------
__global__ void k_fill(const int* __restrict__ ei, int* __restrict__ cursor,
                       int* __restrict__ eidx){
    int e = blockIdx.x * 256 + threadIdx.x;
    if (e < N_EDGES){
        int d = ei[N_EDGES + e];
        int pos = atomicAdd(&cursor[d], 1);
        eidx[pos] = e;
    }
}

// ---------- K3: eh = gelu(edge_attr @ e1_w + e1_b) for ALL layers, [l][k][e] f32 ----------
__global__ void k_edge_mlp(const float* __restrict__ ea, const float* __restrict__ w1,
                           const float* __restrict__ b1, float* __restrict__ ehT){
    __shared__ float as[BFEAT];
    int e = blockIdx.x, o = threadIdx.x;
    if (o < BFEAT) as[o] = ea[e * BFEAT + o];
    __syncthreads();
    #pragma unroll
    for (int l = 0; l < NL; ++l){
        float v = b1[l * H + o];
        #pragma unroll
        for (int f = 0; f < BFEAT; ++f) v += as[f] * w1[(l * BFEAT + f) * H + o];
        v = gelu_exact(v);
        ehT[((size_t)l * KS + o) * N_EDGES + e] = v;
        if (o == 0) ehT[((size_t)l * KS + H) * N_EDGES + e] = 1.0f;   // bias slice
    }
}

// ---------- K4: the big fused GEMM: parts[split][e][o] = sum_k eh[e,k]*(g[e] @ B_k) ----------
// REG-STREAMED B, no LDS round-trip (r6 showed the 3 pipes serialize: MFMA
// 620 + L1 512 + LDS 512 cy/slice-unit = measured 1654). Wave = 64 edges x
// 16 cols; B fragment = 4 dwordx4 from L2 per slice, X/Y register double
// buffer; block = 4 waves sharing one e-tile (ehs f32 in 8.4 KB LDS). Grid
// 1024 = 4 blocks/CU -> 16 waves/CU for pipe overlap; no k-loop barriers.
__global__ __launch_bounds__(256, 2)
void k_msg_gemm(const short* __restrict__ bt, const float* __restrict__ ehT,
                const short* __restrict__ hb, const int* __restrict__ ei,
                float* __restrict__ parts, int l){
    __shared__ __align__(16) float ehs[33 * TILE_E];

    const int tid  = threadIdx.x;
    const int lane = tid & 63, w = tid >> 6;   // 4 waves
    const int col  = lane & 15, quad = lane >> 4;

    const int split = blockIdx.x & 3;
    const int ohalf = (blockIdx.x >> 2) & 1;
    const int tile  = blockIdx.x >> 3;
    const int t     = ohalf * 4 + w;           // o-tile 0..7 (16 cols each)
    const int kbeg  = (KS * split) >> 2;
    const int kend  = (KS * (split + 1)) >> 2;
    const int kcnt  = kend - kbeg;             // 32 (33 for split 3)
    const int ebase = tile * TILE_E;

    // stage eh slice [kcnt][64] (f32) once, shared by the 4 waves
    for (int idx = tid; idx < kcnt * TILE_E; idx += 256){
        int kk = idx >> 6, e = idx & 63;
        ehs[idx] = ehT[((size_t)(l * KS + kbeg + kk)) * N_EDGES + ebase + e];
    }

    // load G fragments (A-operand, loop-invariant): gf[msub][ichunk]
    short8 gf[4][4];
    #pragma unroll
    for (int m = 0; m < 4; ++m){
        int e = ebase + m * 16 + col;
        int s = ei[e];
        const char* gb = (const char*)hb + ((size_t)s * H + quad * 8) * 2;
        #pragma unroll
        for (int ic = 0; ic < 4; ++ic)
            gf[m][ic] = *(const short8*)(gb + ic * 64);
    }

    float acc[4][4];
    #pragma unroll
    for (int m = 0; m < 4; ++m)
        #pragma unroll
        for (int r = 0; r < 4; ++r) acc[m][r] = 0.0f;

    // per-lane base into this wave's o-tile of the B stream
    const char* bsrc = (const char*)bt + (size_t)(l * KS + kbeg) * SLICE_BYTES
                     + t * 4096 + lane * 16;

    short8 X[4], Y[4];

    auto loadB = [&](short8 (&B)[4], int kk){
        const char* p = bsrc + (size_t)kk * SLICE_BYTES;
        #pragma unroll
        for (int ic = 0; ic < 4; ++ic)
            B[ic] = *(const short8*)(p + ic * 1024);
    };
    auto computeB = [&](const short8 (&B)[4], int kk){
        __builtin_amdgcn_s_setprio(1);
        #pragma unroll
        for (int m = 0; m < 4; ++m){
            f32x4 ev = *(const f32x4*)(ehs + kk * TILE_E + m * 16 + quad * 4);
            f32x4 U = {0.0f, 0.0f, 0.0f, 0.0f};
            #pragma unroll
            for (int ic = 0; ic < 4; ++ic)
                U = __builtin_amdgcn_mfma_f32_16x16x32_bf16(gf[m][ic], B[ic], U, 0, 0, 0);
            #pragma unroll
            for (int r = 0; r < 4; ++r)
                acc[m][r] += ev[r] * U[r];
        }
        __builtin_amdgcn_s_setprio(0);
    };

    loadB(X, 0);
    __syncthreads();   // ehs visible (one-time; also drains prologue, fine)

    int kk = 0;
    for (; kk + 2 <= kcnt; kk += 2){
        loadB(Y, kk + 1);
        computeB(X, kk);
        if (kk + 2 < kcnt) loadB(X, kk + 2);
        computeB(Y, kk + 1);
    }
    if (kk < kcnt) computeB(X, kk);      // odd tail (split 3, kcnt=33)

    // epilogue: plain stores of the split-partial (wave-exclusive 16 cols)
    float* pb = parts + (size_t)split * N_EDGES * H + (size_t)ebase * H + t * 16;
    #pragma unroll
    for (int m = 0; m < 4; ++m)
        #pragma unroll
        for (int r = 0; r < 4; ++r)
            pb[(size_t)(m * 16 + quad * 4 + r) * H + col] = acc[m][r];
}

// ---------- K5: node update with fused CSR gather over split partials ----------
__global__ void k_node(const float* __restrict__ parts, const int* __restrict__ eidx,
                       const int* __restrict__ row_ptr,
                       const float* __restrict__ rw, const float* __restrict__ cb,
                       const float* __restrict__ lg, const float* __restrict__ lb,
                       float* __restrict__ h, short* __restrict__ hb, int l){
    __shared__ float hs[H];
    __shared__ float rsum[2], rsq[2];
    int n = blockIdx.x, o = threadIdx.x;
    float hv = h[(size_t)n * H + o];
    hs[o] = hv;
    int p0 = row_ptr[n], p1 = row_ptr[n + 1];
    float a = 0.0f;
    for (int p = p0; p < p1; ++p){
        const float* pr = parts + (size_t)eidx[p] * H + o;
        #pragma unroll
        for (int s = 0; s < SPLITS; ++s) a += pr[(size_t)s * N_EDGES * H];
    }
    int d = p1 - p0;
    a *= 1.0f / (float)(d > 0 ? d : 1);
    __syncthreads();
    float root = cb[l * H + o];
    const float* W = rw + (size_t)l * H * H;
    #pragma unroll 8
    for (int i = 0; i < H; ++i) root += hs[i] * W[i * H + o];
    float hn = fmaxf(a + root, 0.0f);
    float v  = hv + hn;
    float s = v, q = v * v;
    #pragma unroll
    for (int off = 32; off > 0; off >>= 1){
        s += __shfl_down(s, off, 64);
        q += __shfl_down(q, off, 64);
    }
    if ((o & 63) == 0){ rsum[o >> 6] = s; rsq[o >> 6] = q; }
    __syncthreads();
    float S = rsum[0] + rsum[1], Q = rsq[0] + rsq[1];
    float mean = S * (1.0f / H);
    float var  = Q * (1.0f / H) - mean * mean;
    float out  = (v - mean) * rsqrtf(var + 1e-5f) * lg[l * H + o] + lb[l * H + o];
    h[(size_t)n * H + o]  = out;
    hb[(size_t)n * H + o] = f2b(out);
}

// ---------- K6: global mean-pool accumulation ----------
__global__ void k_pool(const float* __restrict__ h, const int* __restrict__ batch,
                       float* __restrict__ molsum, float* __restrict__ cnt){
    int idx = blockIdx.x * 256 + threadIdx.x;    // N*H
    int n = idx >> 7, o = idx & 127;
    int b = batch[n];
    atomicAdd(&molsum[b * H + o], h[idx]);
    if (o == 0) atomicAdd(&cnt[b], 1.0f);
}

// ---------- K7: head MLP ----------
__global__ void k_head(const float* __restrict__ molsum, const float* __restrict__ cnt,
                       const float* __restrict__ w1, const float* __restrict__ b1,
                       const float* __restrict__ w2, const float* __restrict__ b2,
                       float* __restrict__ out){
    __shared__ float mol[H];
    int g = blockIdx.x, t = threadIdx.x;   // 64 threads = 1 wave
    float c = fmaxf(cnt[g], 1.0f);
    mol[t]      = molsum[g * H + t] / c;
    mol[t + 64] = molsum[g * H + t + 64] / c;
    __syncthreads();
    float a = b1[t];
    #pragma unroll 8
    for (int i = 0; i < H; ++i) a += mol[i] * w1[i * 64 + t];
    float hid = gelu_exact(a);
    float p = hid * w2[t];
    #pragma unroll
    for (int off = 32; off > 0; off >>= 1) p += __shfl_down(p, off, 64);
    if (t == 0) out[g] = p + b2[0];
}

extern "C" void kernel_launch(void* const* d_in, const int* in_sizes, int n_in,
                              void* d_out, int out_size, void* d_ws, size_t ws_size,
                              hipStream_t stream){
    (void)in_sizes; (void)n_in; (void)out_size; (void)ws_size;
    const float* x     = (const float*)d_in[0];
    const int*   ei    = (const int*)  d_in[1];
    const float* ea    = (const float*)d_in[2];
    const int*   batch = (const int*)  d_in[3];
    const float* aw    = (const float*)d_in[4];
    const float* ab    = (const float*)d_in[5];
    const float* e1w   = (const float*)d_in[6];
    const float* e1b   = (const float*)d_in[7];
    const float* e2w   = (const float*)d_in[8];
    const float* e2b   = (const float*)d_in[9];
    const float* rw    = (const float*)d_in[10];
    const float* cb    = (const float*)d_in[11];
    const float* lg    = (const float*)d_in[12];
    const float* lb    = (const float*)d_in[13];
    const float* hw1   = (const float*)d_in[14];
    const float* hb1   = (const float*)d_in[15];
    const float* hw2   = (const float*)d_in[16];
    const float* hb2   = (const float*)d_in[17];
    float* out = (float*)d_out;

    char* p = (char*)d_ws;
    auto carve = [&](size_t bytes){ char* r = p; p += (bytes + 255) & ~(size_t)255; return r; };
    short* bt     = (short*)carve((size_t)NL * KS * SLICE_SH * 2);    // 12.7 MB
    float* h      = (float*)carve((size_t)N_NODES * H * 4);           // 2 MB
    short* hbuf   = (short*)carve((size_t)N_NODES * H * 2);           // 1 MB
    float* ehT    = (float*)carve((size_t)NL * KS * N_EDGES * 4);     // 12.7 MB
    float* parts  = (float*)carve((size_t)SPLITS * N_EDGES * H * 4);  // 16.7 MB
    int*   ideg   = (int*)  carve((size_t)N_NODES * 4);
    int*   row_ptr= (int*)  carve((size_t)(N_NODES + 1) * 4);
    int*   cursor = (int*)  carve((size_t)N_NODES * 4);
    int*   eidx   = (int*)  carve((size_t)N_EDGES * 4);
    float* molsum = (float*)carve((size_t)NGRAPH * H * 4);
    float* cnt    = (float*)carve((size_t)NGRAPH * 4);

    hipMemsetAsync(ideg, 0, (size_t)N_NODES * 4, stream);
    hipMemsetAsync(molsum, 0, (size_t)NGRAPH * H * 4, stream);
    hipMemsetAsync(cnt, 0, (size_t)NGRAPH * 4, stream);

    k_prep_b<<<NL * KS * 4, 256, 0, stream>>>(e2w, e2b, bt);
    k_atom<<<N_NODES, H, 0, stream>>>(x, aw, ab, h, hbuf);
    k_deg<<<N_EDGES / 256, 256, 0, stream>>>(ei, ideg);
    k_scan<<<1, 256, 0, stream>>>(ideg, row_ptr, cursor);
    k_fill<<<N_EDGES / 256, 256, 0, stream>>>(ei, cursor, eidx);
    k_edge_mlp<<<N_EDGES, H, 0, stream>>>(ea, e1w, e1b, ehT);

    for (int l = 0; l < NL; ++l){
        k_msg_gemm<<<(N_EDGES / TILE_E) * 2 * SPLITS, 256, 0, stream>>>(bt, ehT, hbuf, ei, parts, l);
        k_node<<<N_NODES, H, 0, stream>>>(parts, eidx, row_ptr, rw, cb, lg, lb, h, hbuf, l);
    }
    k_pool<<<N_NODES * H / 256, 256, 0, stream>>>(h, batch, molsum, cnt);
    k_head<<<NGRAPH, 64, 0, stream>>>(molsum, cnt, hw1, hb1, hw2, hb2, out);
}

// Round 8
// 313.647 us; speedup vs baseline: 1.0217x; 1.0217x over previous
//
#include <hip/hip_runtime.h>
#include <hip/hip_bf16.h>

#define N_NODES 4096
#define N_EDGES 8192
#define NGRAPH  256
#define AFEAT   9
#define BFEAT   4
#define H       128
#define NL      3
#define KS      129              // k-slices including the e2_b bias slice
#define SPLITS  3                // 129 = 3 x 43 exactly; grid 768 = 3 blocks/CU exactly
#define KSPL    43
#define TILE_E  64
#define NPB     4                // nodes per k_node block
#define SLICE_SH    16384        // shorts per k-slice (chunked layout)
#define SLICE_BYTES 32768        // bytes per k-slice

typedef short short8 __attribute__((ext_vector_type(8)));
typedef float f32x4 __attribute__((ext_vector_type(4)));

// ---- bf16 helpers (RNE, finite inputs) ----
__device__ __forceinline__ short f2b(float f){
    union { float f; unsigned u; } c; c.f = f;
    unsigned r = c.u + 0x7FFFu + ((c.u >> 16) & 1u);
    return (short)(r >> 16);
}
__device__ __forceinline__ float gelu_exact(float x){
    return 0.5f * x * (1.0f + erff(x * 0.70710678118654752440f));
}

// ---------- K0: e2_w/e2_b -> bt[l][k] in fragment-chunk order ----------
// Element B_k[i][o] stored at short offset
// (((o>>4)*4 + (i>>5))*64 + ((i>>3)&3)*16 + (o&15))*8 + (i&7).
// For fixed (o-tile t, ic): a wave's B fragment is the contiguous aligned
// 1 KB line at byte off (t*4+ic)*1024 + lane*16 -> one perfectly-coalesced
// global_load_dwordx4 per (t,ic) straight into registers.
__global__ void k_prep_b(const float* __restrict__ e2w, const float* __restrict__ e2b,
                         short* __restrict__ bt){
    __shared__ float ts[H][33];
    int b  = blockIdx.x;
    int o0 = (b & 3) * 32;
    int k  = (b >> 2) % KS;
    int l  = (b >> 2) / KS;
    const float* src = (k < H) ? (e2w + ((size_t)l * H + k) * (H * H))
                               : (e2b + (size_t)l * (H * H));
    for (int idx = threadIdx.x; idx < H * 32; idx += 256){
        int i = idx >> 5, op = idx & 31;
        ts[i][op] = src[i * H + o0 + op];
    }
    __syncthreads();
    short* dst = bt + (size_t)(l * KS + k) * SLICE_SH;
    for (int idx = threadIdx.x; idx < 32 * H; idx += 256){
        int j    = idx & 7;
        int quad = (idx >> 3) & 3;
        int op   = (idx >> 5) & 31;
        int ic   = idx >> 10;
        int i    = ic * 32 + quad * 8 + j;
        int o    = o0 + op;
        dst[((((o >> 4) * 4 + ic) * 64) + quad * 16 + (o & 15)) * 8 + j] = f2b(ts[i][op]);
    }
}

// ---------- K1: h0 = relu(x @ atom_w + atom_b) ----------
__global__ void k_atom(const float* __restrict__ x, const float* __restrict__ aw,
                       const float* __restrict__ ab, float* __restrict__ h,
                       short* __restrict__ hb){
    __shared__ float xs[AFEAT];
    int n = blockIdx.x, o = threadIdx.x;
    if (o < AFEAT) xs[o] = x[n * AFEAT + o];
    __syncthreads();
    float a = ab[o];
    #pragma unroll
    for (int f = 0; f < AFEAT; ++f) a += xs[f] * aw[f * H + o];
    a = fmaxf(a, 0.0f);
    h[(size_t)n * H + o]  = a;
    hb[(size_t)n * H + o] = f2b(a);
}

// ---------- K2: in-degree (int histogram) ----------
__global__ void k_deg(const int* __restrict__ ei, int* __restrict__ ideg){
    int e = blockIdx.x * 256 + threadIdx.x;
    if (e < N_EDGES) atomicAdd(&ideg[ei[N_EDGES + e]], 1);
}

// ---------- K2b: exclusive scan -> row_ptr + cursor (one block, once) ----------
__global__ void k_scan(const int* __restrict__ ideg, int* __restrict__ row_ptr,
                       int* __restrict__ cursor){
    __shared__ int part[256];
    int t = threadIdx.x;
    int base = t * 16;
    int loc[16]; int s = 0;
    #pragma unroll
    for (int i = 0; i < 16; ++i){ loc[i] = s; s += ideg[base + i]; }
    part[t] = s;
    __syncthreads();
    if (t == 0){
        int run = 0;
        for (int i = 0; i < 256; ++i){ int v = part[i]; part[i] = run; run += v; }
        row_ptr[N_NODES] = run;
    }
    __syncthreads();
    int off = part[t];
    #pragma unroll
    for (int i = 0; i < 16; ++i){
        row_ptr[base + i] = off + loc[i];
        cursor[base + i]  = off + loc[i];
    }
}

// ---------- K2c: fill CSR edge-id list (once) ----------
__global__ void k_fill(const int* __restrict__ ei, int* __restrict__ cursor,
                       int* __restrict__ eidx){
    int e = blockIdx.x * 256 + threadIdx.x;
    if (e < N_EDGES){
        int d = ei[N_EDGES + e];
        int pos = atomicAdd(&cursor[d], 1);
        eidx[pos] = e;
    }
}

// ---------- K3: eh = gelu(edge_attr @ e1_w + e1_b), [l][k][e] f32 ----------
// Transposed mapping: block = (one output-dim o) x (256 contiguous edges).
// Weights w1/b1 become wave-uniform scalar loads; ehT stores are fully
// coalesced in e (the old o=thread mapping scattered every lane's 4B store
// onto a different cache line -- 3.1M uncoalesced stores).
__global__ void k_edge_mlp(const float* __restrict__ ea, const float* __restrict__ w1,
                           const float* __restrict__ b1, float* __restrict__ ehT){
    int o = blockIdx.x >> 5;                       // 0..127
    int e = (blockIdx.x & 31) * 256 + threadIdx.x; // 0..8191
    float4 a = *(const float4*)(ea + (size_t)e * BFEAT);
    #pragma unroll
    for (int l = 0; l < NL; ++l){
        float v = b1[l * H + o]
                + a.x * w1[(l * BFEAT + 0) * H + o]
                + a.y * w1[(l * BFEAT + 1) * H + o]
                + a.z * w1[(l * BFEAT + 2) * H + o]
                + a.w * w1[(l * BFEAT + 3) * H + o];
        v = gelu_exact(v);
        ehT[((size_t)l * KS + o) * N_EDGES + e] = v;
        if (o == 0) ehT[((size_t)l * KS + H) * N_EDGES + e] = 1.0f;   // bias slice
    }
}

// ---------- K4: the big fused GEMM: parts[split][e][o] = sum_k eh[e,k]*(g[e] @ B_k) ----------
// Reg-streamed B (r6 showed LDS round-trip serializes), now with DEPTH-2
// prefetch: X/Y/Z named register buffers (rule: no runtime-indexed reg
// arrays), ~640 cy of latency cover vs L2 ~300. SPLITS=3 -> kcnt=43 exact,
// grid 768 = 3 blocks/CU exact (matches 3 waves/SIMD at ~150 VGPR), no
// ragged occupancy tail. No barriers in the k-loop.
__global__ __launch_bounds__(256, 2)
void k_msg_gemm(const short* __restrict__ bt, const float* __restrict__ ehT,
                const short* __restrict__ hb, const int* __restrict__ ei,
                float* __restrict__ parts, int l){
    __shared__ __align__(16) float ehs[KSPL * TILE_E];

    const int tid  = threadIdx.x;
    const int lane = tid & 63, w = tid >> 6;   // 4 waves
    const int col  = lane & 15, quad = lane >> 4;

    const int split = blockIdx.x % 3;
    const int rest  = blockIdx.x / 3;
    const int ohalf = rest & 1;
    const int tile  = rest >> 1;
    const int t     = ohalf * 4 + w;           // o-tile 0..7 (16 cols each)
    const int kbeg  = split * KSPL;
    const int kcnt  = KSPL;                    // 43, all splits
    const int ebase = tile * TILE_E;

    // stage eh slice [kcnt][64] (f32) once, shared by the 4 waves
    for (int idx = tid; idx < kcnt * TILE_E; idx += 256){
        int kk = idx >> 6, e = idx & 63;
        ehs[idx] = ehT[((size_t)(l * KS + kbeg + kk)) * N_EDGES + ebase + e];
    }

    // load G fragments (A-operand, loop-invariant): gf[msub][ichunk]
    short8 gf[4][4];
    #pragma unroll
    for (int m = 0; m < 4; ++m){
        int e = ebase + m * 16 + col;
        int s = ei[e];
        const char* gb = (const char*)hb + ((size_t)s * H + quad * 8) * 2;
        #pragma unroll
        for (int ic = 0; ic < 4; ++ic)
            gf[m][ic] = *(const short8*)(gb + ic * 64);
    }

    float acc[4][4];
    #pragma unroll
    for (int m = 0; m < 4; ++m)
        #pragma unroll
        for (int r = 0; r < 4; ++r) acc[m][r] = 0.0f;

    // per-lane base into this wave's o-tile of the B stream
    const char* bsrc = (const char*)bt + (size_t)(l * KS + kbeg) * SLICE_BYTES
                     + t * 4096 + lane * 16;

    short8 X[4], Y[4], Z[4];

    auto loadB = [&](short8 (&B)[4], int kk){
        const char* p = bsrc + (size_t)kk * SLICE_BYTES;
        #pragma unroll
        for (int ic = 0; ic < 4; ++ic)
            B[ic] = *(const short8*)(p + ic * 1024);
    };
    auto computeB = [&](const short8 (&B)[4], int kk){
        __builtin_amdgcn_s_setprio(1);
        #pragma unroll
        for (int m = 0; m < 4; ++m){
            f32x4 ev = *(const f32x4*)(ehs + kk * TILE_E + m * 16 + quad * 4);
            f32x4 U = {0.0f, 0.0f, 0.0f, 0.0f};
            #pragma unroll
            for (int ic = 0; ic < 4; ++ic)
                U = __builtin_amdgcn_mfma_f32_16x16x32_bf16(gf[m][ic], B[ic], U, 0, 0, 0);
            #pragma unroll
            for (int r = 0; r < 4; ++r)
                acc[m][r] += ev[r] * U[r];
        }
        __builtin_amdgcn_s_setprio(0);
    };

    loadB(X, 0); loadB(Y, 1); loadB(Z, 2);     // kcnt = 43 >= 3 always
    __syncthreads();   // ehs visible (one-time)

    int kk = 0;
    for (; kk + 3 < kcnt; kk += 3){
        computeB(X, kk);     loadB(X, kk + 3);
        computeB(Y, kk + 1); if (kk + 4 < kcnt) loadB(Y, kk + 4);
        computeB(Z, kk + 2); if (kk + 5 < kcnt) loadB(Z, kk + 5);
    }
    // kcnt - kk in {1,2,3}; buffers already loaded
    computeB(X, kk);
    if (kk + 1 < kcnt) computeB(Y, kk + 1);
    if (kk + 2 < kcnt) computeB(Z, kk + 2);

    // epilogue: plain stores of the split-partial (wave-exclusive 16 cols)
    float* pb = parts + (size_t)split * N_EDGES * H + (size_t)ebase * H + t * 16;
    #pragma unroll
    for (int m = 0; m < 4; ++m)
        #pragma unroll
        for (int r = 0; r < 4; ++r)
            pb[(size_t)(m * 16 + quad * 4 + r) * H + col] = acc[m][r];
}

// ---------- K5: node update, 4 nodes/block (root_w traffic /4), fused pool on last layer ----------
__global__ void k_node(const float* __restrict__ parts, const int* __restrict__ eidx,
                       const int* __restrict__ row_ptr,
                       const float* __restrict__ rw, const float* __restrict__ cb,
                       const float* __restrict__ lg, const float* __restrict__ lb,
                       float* __restrict__ h, short* __restrict__ hb,
                       const int* __restrict__ batch, float* __restrict__ molsum,
                       float* __restrict__ cnt, int l, int dolast){
    __shared__ float hs[NPB][H];
    __shared__ float red[NPB][2][2];           // [node][sum/sq][wavehalf]
    int n0 = blockIdx.x * NPB, o = threadIdx.x;
    const float* W = rw + (size_t)l * H * H;

    float hv[NPB], root[NPB], a[NPB];
    #pragma unroll
    for (int m = 0; m < NPB; ++m){
        hv[m] = h[(size_t)(n0 + m) * H + o];
        hs[m][o] = hv[m];
        root[m] = cb[l * H + o];
    }
    __syncthreads();

    // CSR gather of split partials
    #pragma unroll
    for (int m = 0; m < NPB; ++m){
        int p0 = row_ptr[n0 + m], p1 = row_ptr[n0 + m + 1];
        float s = 0.0f;
        for (int p = p0; p < p1; ++p){
            const float* pr = parts + (size_t)eidx[p] * H + o;
            #pragma unroll
            for (int sp = 0; sp < SPLITS; ++sp) s += pr[(size_t)sp * N_EDGES * H];
        }
        int d = p1 - p0;
        a[m] = s / (float)(d > 0 ? d : 1);
    }

    // root transform: one W read serves 4 nodes
    #pragma unroll 8
    for (int i = 0; i < H; ++i){
        float wv = W[i * H + o];
        #pragma unroll
        for (int m = 0; m < NPB; ++m) root[m] += hs[m][i] * wv;
    }

    float v[NPB];
    #pragma unroll
    for (int m = 0; m < NPB; ++m){
        float hn = fmaxf(a[m] + root[m], 0.0f);
        v[m] = hv[m] + hn;
        float s = v[m], q = v[m] * v[m];
        #pragma unroll
        for (int off = 32; off > 0; off >>= 1){
            s += __shfl_down(s, off, 64);
            q += __shfl_down(q, off, 64);
        }
        if ((o & 63) == 0){ red[m][0][o >> 6] = s; red[m][1][o >> 6] = q; }
    }
    __syncthreads();
    #pragma unroll
    for (int m = 0; m < NPB; ++m){
        float S = red[m][0][0] + red[m][0][1];
        float Q = red[m][1][0] + red[m][1][1];
        float mean = S * (1.0f / H);
        float var  = Q * (1.0f / H) - mean * mean;
        float out  = (v[m] - mean) * rsqrtf(var + 1e-5f) * lg[l * H + o] + lb[l * H + o];
        int n = n0 + m;
        h[(size_t)n * H + o]  = out;
        hb[(size_t)n * H + o] = f2b(out);
        if (dolast){
            int b = batch[n];
            atomicAdd(&molsum[b * H + o], out);
            if (o == 0) atomicAdd(&cnt[b], 1.0f);
        }
    }
}

// ---------- K7: head MLP ----------
__global__ void k_head(const float* __restrict__ molsum, const float* __restrict__ cnt,
                       const float* __restrict__ w1, const float* __restrict__ b1,
                       const float* __restrict__ w2, const float* __restrict__ b2,
                       float* __restrict__ out){
    __shared__ float mol[H];
    int g = blockIdx.x, t = threadIdx.x;   // 64 threads = 1 wave
    float c = fmaxf(cnt[g], 1.0f);
    mol[t]      = molsum[g * H + t] / c;
    mol[t + 64] = molsum[g * H + t + 64] / c;
    __syncthreads();
    float a = b1[t];
    #pragma unroll 8
    for (int i = 0; i < H; ++i) a += mol[i] * w1[i * 64 + t];
    float hid = gelu_exact(a);
    float p = hid * w2[t];
    #pragma unroll
    for (int off = 32; off > 0; off >>= 1) p += __shfl_down(p, off, 64);
    if (t == 0) out[g] = p + b2[0];
}

extern "C" void kernel_launch(void* const* d_in, const int* in_sizes, int n_in,
                              void* d_out, int out_size, void* d_ws, size_t ws_size,
                              hipStream_t stream){
    (void)in_sizes; (void)n_in; (void)out_size; (void)ws_size;
    const float* x     = (const float*)d_in[0];
    const int*   ei    = (const int*)  d_in[1];
    const float* ea    = (const float*)d_in[2];
    const int*   batch = (const int*)  d_in[3];
    const float* aw    = (const float*)d_in[4];
    const float* ab    = (const float*)d_in[5];
    const float* e1w   = (const float*)d_in[6];
    const float* e1b   = (const float*)d_in[7];
    const float* e2w   = (const float*)d_in[8];
    const float* e2b   = (const float*)d_in[9];
    const float* rw    = (const float*)d_in[10];
    const float* cb    = (const float*)d_in[11];
    const float* lg    = (const float*)d_in[12];
    const float* lb    = (const float*)d_in[13];
    const float* hw1   = (const float*)d_in[14];
    const float* hb1   = (const float*)d_in[15];
    const float* hw2   = (const float*)d_in[16];
    const float* hb2   = (const float*)d_in[17];
    float* out = (float*)d_out;

    char* p = (char*)d_ws;
    auto carve = [&](size_t bytes){ char* r = p; p += (bytes + 255) & ~(size_t)255; return r; };
    short* bt     = (short*)carve((size_t)NL * KS * SLICE_SH * 2);    // 12.7 MB
    float* h      = (float*)carve((size_t)N_NODES * H * 4);           // 2 MB
    short* hbuf   = (short*)carve((size_t)N_NODES * H * 2);           // 1 MB
    float* ehT    = (float*)carve((size_t)NL * KS * N_EDGES * 4);     // 12.7 MB
    float* parts  = (float*)carve((size_t)SPLITS * N_EDGES * H * 4);  // 12.6 MB
    int*   ideg   = (int*)  carve((size_t)N_NODES * 4);
    int*   row_ptr= (int*)  carve((size_t)(N_NODES + 1) * 4);
    int*   cursor = (int*)  carve((size_t)N_NODES * 4);
    int*   eidx   = (int*)  carve((size_t)N_EDGES * 4);
    float* molsum = (float*)carve((size_t)NGRAPH * H * 4);
    float* cnt    = (float*)carve((size_t)NGRAPH * 4);

    hipMemsetAsync(ideg, 0, (size_t)N_NODES * 4, stream);
    hipMemsetAsync(molsum, 0, (size_t)NGRAPH * H * 4, stream);
    hipMemsetAsync(cnt, 0, (size_t)NGRAPH * 4, stream);

    k_prep_b<<<NL * KS * 4, 256, 0, stream>>>(e2w, e2b, bt);
    k_atom<<<N_NODES, H, 0, stream>>>(x, aw, ab, h, hbuf);
    k_deg<<<N_EDGES / 256, 256, 0, stream>>>(ei, ideg);
    k_scan<<<1, 256, 0, stream>>>(ideg, row_ptr, cursor);
    k_fill<<<N_EDGES / 256, 256, 0, stream>>>(ei, cursor, eidx);
    k_edge_mlp<<<H * (N_EDGES / 256), 256, 0, stream>>>(ea, e1w, e1b, ehT);

    for (int l = 0; l < NL; ++l){
        k_msg_gemm<<<(N_EDGES / TILE_E) * 2 * SPLITS, 256, 0, stream>>>(bt, ehT, hbuf, ei, parts, l);
        k_node<<<N_NODES / NPB, H, 0, stream>>>(parts, eidx, row_ptr, rw, cb, lg, lb,
                                                h, hbuf, batch, molsum, cnt, l,
                                                l == NL - 1 ? 1 : 0);
    }
    k_head<<<NGRAPH, 64, 0, stream>>>(molsum, cnt, hw1, hb1, hw2, hb2, out);
}

// Round 9
// 293.494 us; speedup vs baseline: 1.0919x; 1.0687x over previous
//
#include <hip/hip_runtime.h>
#include <hip/hip_bf16.h>

#define N_NODES 4096
#define N_EDGES 8192
#define NGRAPH  256
#define AFEAT   9
#define BFEAT   4
#define H       128
#define NL      3
#define KS      129              // k-slices including the e2_b bias slice
#define SPLITS  4                // x 2 o-halves = 8 = XCD count: bid&7 pins L2
#define TILE_E  64
#define NPB     4                // nodes per k_node block
#define SLICE_SH    16384        // shorts per k-slice (chunked layout)
#define SLICE_BYTES 32768        // bytes per k-slice

typedef short short8 __attribute__((ext_vector_type(8)));
typedef float f32x4 __attribute__((ext_vector_type(4)));

// ---- bf16 helpers (RNE, finite inputs) ----
__device__ __forceinline__ short f2b(float f){
    union { float f; unsigned u; } c; c.f = f;
    unsigned r = c.u + 0x7FFFu + ((c.u >> 16) & 1u);
    return (short)(r >> 16);
}
__device__ __forceinline__ float gelu_exact(float x){
    return 0.5f * x * (1.0f + erff(x * 0.70710678118654752440f));
}

// ---------- K0: e2_w/e2_b -> bt[l][k] in fragment-chunk order ----------
// Element B_k[i][o] stored at short offset
// (((o>>4)*4 + (i>>5))*64 + ((i>>3)&3)*16 + (o&15))*8 + (i&7).
// For fixed (o-tile t, ic): a wave's B fragment is the contiguous aligned
// 1 KB line at byte off (t*4+ic)*1024 + lane*16 -> one perfectly-coalesced
// global_load_dwordx4 per (t,ic) straight into registers.
__global__ void k_prep_b(const float* __restrict__ e2w, const float* __restrict__ e2b,
                         short* __restrict__ bt){
    __shared__ float ts[H][33];
    int b  = blockIdx.x;
    int o0 = (b & 3) * 32;
    int k  = (b >> 2) % KS;
    int l  = (b >> 2) / KS;
    const float* src = (k < H) ? (e2w + ((size_t)l * H + k) * (H * H))
                               : (e2b + (size_t)l * (H * H));
    for (int idx = threadIdx.x; idx < H * 32; idx += 256){
        int i = idx >> 5, op = idx & 31;
        ts[i][op] = src[i * H + o0 + op];
    }
    __syncthreads();
    short* dst = bt + (size_t)(l * KS + k) * SLICE_SH;
    for (int idx = threadIdx.x; idx < 32 * H; idx += 256){
        int j    = idx & 7;
        int quad = (idx >> 3) & 3;
        int op   = (idx >> 5) & 31;
        int ic   = idx >> 10;
        int i    = ic * 32 + quad * 8 + j;
        int o    = o0 + op;
        dst[((((o >> 4) * 4 + ic) * 64) + quad * 16 + (o & 15)) * 8 + j] = f2b(ts[i][op]);
    }
}

// ---------- K1: h0 = relu(x @ atom_w + atom_b) ----------
__global__ void k_atom(const float* __restrict__ x, const float* __restrict__ aw,
                       const float* __restrict__ ab, float* __restrict__ h,
                       short* __restrict__ hb){
    __shared__ float xs[AFEAT];
    int n = blockIdx.x, o = threadIdx.x;
    if (o < AFEAT) xs[o] = x[n * AFEAT + o];
    __syncthreads();
    float a = ab[o];
    #pragma unroll
    for (int f = 0; f < AFEAT; ++f) a += xs[f] * aw[f * H + o];
    a = fmaxf(a, 0.0f);
    h[(size_t)n * H + o]  = a;
    hb[(size_t)n * H + o] = f2b(a);
}

// ---------- K2: in-degree (int histogram) ----------
__global__ void k_deg(const int* __restrict__ ei, int* __restrict__ ideg){
    int e = blockIdx.x * 256 + threadIdx.x;
    if (e < N_EDGES) atomicAdd(&ideg[ei[N_EDGES + e]], 1);
}

// ---------- K2b: exclusive scan -> row_ptr + cursor (one block, once) ----------
__global__ void k_scan(const int* __restrict__ ideg, int* __restrict__ row_ptr,
                       int* __restrict__ cursor){
    __shared__ int part[256];
    int t = threadIdx.x;
    int base = t * 16;
    int loc[16]; int s = 0;
    #pragma unroll
    for (int i = 0; i < 16; ++i){ loc[i] = s; s += ideg[base + i]; }
    part[t] = s;
    __syncthreads();
    if (t == 0){
        int run = 0;
        for (int i = 0; i < 256; ++i){ int v = part[i]; part[i] = run; run += v; }
        row_ptr[N_NODES] = run;
    }
    __syncthreads();
    int off = part[t];
    #pragma unroll
    for (int i = 0; i < 16; ++i){
        row_ptr[base + i] = off + loc[i];
        cursor[base + i]  = off + loc[i];
    }
}

// ---------- K2c: fill CSR edge-id list (once) ----------
__global__ void k_fill(const int* __restrict__ ei, int* __restrict__ cursor,
                       int* __restrict__ eidx){
    int e = blockIdx.x * 256 + threadIdx.x;
    if (e < N_EDGES){
        int d = ei[N_EDGES + e];
        int pos = atomicAdd(&cursor[d], 1);
        eidx[pos] = e;
    }
}

// ---------- K3: eh = gelu(edge_attr @ e1_w + e1_b), [l][k][e] f32 ----------
// Transposed mapping: block = (one output-dim o) x (256 contiguous edges):
// wave-uniform weight loads, fully-coalesced ehT stores.
__global__ void k_edge_mlp(const float* __restrict__ ea, const float* __restrict__ w1,
                           const float* __restrict__ b1, float* __restrict__ ehT){
    int o = blockIdx.x >> 5;                       // 0..127
    int e = (blockIdx.x & 31) * 256 + threadIdx.x; // 0..8191
    float4 a = *(const float4*)(ea + (size_t)e * BFEAT);
    #pragma unroll
    for (int l = 0; l < NL; ++l){
        float v = b1[l * H + o]
                + a.x * w1[(l * BFEAT + 0) * H + o]
                + a.y * w1[(l * BFEAT + 1) * H + o]
                + a.z * w1[(l * BFEAT + 2) * H + o]
                + a.w * w1[(l * BFEAT + 3) * H + o];
        v = gelu_exact(v);
        ehT[((size_t)l * KS + o) * N_EDGES + e] = v;
        if (o == 0) ehT[((size_t)l * KS + H) * N_EDGES + e] = 1.0f;   // bias slice
    }
}

// ---------- K4: the big fused GEMM: parts[split][e][o] = sum_k eh[e,k]*(g[e] @ B_k) ----------
// Reg-streamed B with depth-2 X/Y/Z prefetch. XCD-PINNED: (split,ohalf) =
// bid&7 = the XCD round-robin index, so each XCD's L2 serves exactly one
// 528 KB B-region + 1.1 MB eh-split (+1 MB hbuf) -- all B loads are L2 hits
// (r8: split=bid%3 broke pinning, FETCH 7.8->18.3 MB, B refetched 4x from
// HBM at ~900cy; that was the 2/3 MFMA-idle). Grid 1024 = 4 blocks/CU ->
// 4 waves/SIMD. No barriers in the k-loop.
__global__ __launch_bounds__(256, 2)
void k_msg_gemm(const short* __restrict__ bt, const float* __restrict__ ehT,
                const short* __restrict__ hb, const int* __restrict__ ei,
                float* __restrict__ parts, int l){
    __shared__ __align__(16) float ehs[33 * TILE_E];

    const int tid  = threadIdx.x;
    const int lane = tid & 63, w = tid >> 6;   // 4 waves
    const int col  = lane & 15, quad = lane >> 4;

    const int so    = blockIdx.x & 7;          // XCD id on 8-XCD round-robin
    const int split = so & 3;
    const int ohalf = so >> 2;
    const int tile  = blockIdx.x >> 3;
    const int t     = ohalf * 4 + w;           // o-tile 0..7 (16 cols each)
    const int kbeg  = (KS * split) >> 2;
    const int kend  = (KS * (split + 1)) >> 2;
    const int kcnt  = kend - kbeg;             // 32 (33 for split 3)
    const int ebase = tile * TILE_E;

    // stage eh slice [kcnt][64] (f32) once, shared by the 4 waves
    for (int idx = tid; idx < kcnt * TILE_E; idx += 256){
        int kk = idx >> 6, e = idx & 63;
        ehs[idx] = ehT[((size_t)(l * KS + kbeg + kk)) * N_EDGES + ebase + e];
    }

    // load G fragments (A-operand, loop-invariant): gf[msub][ichunk]
    short8 gf[4][4];
    #pragma unroll
    for (int m = 0; m < 4; ++m){
        int e = ebase + m * 16 + col;
        int s = ei[e];
        const char* gb = (const char*)hb + ((size_t)s * H + quad * 8) * 2;
        #pragma unroll
        for (int ic = 0; ic < 4; ++ic)
            gf[m][ic] = *(const short8*)(gb + ic * 64);
    }

    float acc[4][4];
    #pragma unroll
    for (int m = 0; m < 4; ++m)
        #pragma unroll
        for (int r = 0; r < 4; ++r) acc[m][r] = 0.0f;

    // per-lane base into this wave's o-tile of the B stream
    const char* bsrc = (const char*)bt + (size_t)(l * KS + kbeg) * SLICE_BYTES
                     + t * 4096 + lane * 16;

    short8 X[4], Y[4], Z[4];

    auto loadB = [&](short8 (&B)[4], int kk){
        const char* p = bsrc + (size_t)kk * SLICE_BYTES;
        #pragma unroll
        for (int ic = 0; ic < 4; ++ic)
            B[ic] = *(const short8*)(p + ic * 1024);
    };
    auto computeB = [&](const short8 (&B)[4], int kk){
        __builtin_amdgcn_s_setprio(1);
        #pragma unroll
        for (int m = 0; m < 4; ++m){
            f32x4 ev = *(const f32x4*)(ehs + kk * TILE_E + m * 16 + quad * 4);
            f32x4 U = {0.0f, 0.0f, 0.0f, 0.0f};
            #pragma unroll
            for (int ic = 0; ic < 4; ++ic)
                U = __builtin_amdgcn_mfma_f32_16x16x32_bf16(gf[m][ic], B[ic], U, 0, 0, 0);
            #pragma unroll
            for (int r = 0; r < 4; ++r)
                acc[m][r] += ev[r] * U[r];
        }
        __builtin_amdgcn_s_setprio(0);
    };

    loadB(X, 0); loadB(Y, 1); loadB(Z, 2);     // kcnt >= 32 always
    __syncthreads();   // ehs visible (one-time)

    int kk = 0;
    for (; kk + 3 < kcnt; kk += 3){
        computeB(X, kk);     loadB(X, kk + 3);
        computeB(Y, kk + 1); if (kk + 4 < kcnt) loadB(Y, kk + 4);
        computeB(Z, kk + 2); if (kk + 5 < kcnt) loadB(Z, kk + 5);
    }
    // kcnt - kk in {1,2,3}; buffers already loaded
    computeB(X, kk);
    if (kk + 1 < kcnt) computeB(Y, kk + 1);
    if (kk + 2 < kcnt) computeB(Z, kk + 2);

    // epilogue: plain stores of the split-partial (wave-exclusive 16 cols)
    float* pb = parts + (size_t)split * N_EDGES * H + (size_t)ebase * H + t * 16;
    #pragma unroll
    for (int m = 0; m < 4; ++m)
        #pragma unroll
        for (int r = 0; r < 4; ++r)
            pb[(size_t)(m * 16 + quad * 4 + r) * H + col] = acc[m][r];
}

// ---------- K5: node update, 4 nodes/block (root_w traffic /4), fused pool on last layer ----------
__global__ void k_node(const float* __restrict__ parts, const int* __restrict__ eidx,
                       const int* __restrict__ row_ptr,
                       const float* __restrict__ rw, const float* __restrict__ cb,
                       const float* __restrict__ lg, const float* __restrict__ lb,
                       float* __restrict__ h, short* __restrict__ hb,
                       const int* __restrict__ batch, float* __restrict__ molsum,
                       float* __restrict__ cnt, int l, int dolast){
    __shared__ float hs[NPB][H];
    __shared__ float red[NPB][2][2];           // [node][sum/sq][wavehalf]
    int n0 = blockIdx.x * NPB, o = threadIdx.x;
    const float* W = rw + (size_t)l * H * H;

    float hv[NPB], root[NPB], a[NPB];
    #pragma unroll
    for (int m = 0; m < NPB; ++m){
        hv[m] = h[(size_t)(n0 + m) * H + o];
        hs[m][o] = hv[m];
        root[m] = cb[l * H + o];
    }
    __syncthreads();

    // CSR gather of split partials
    #pragma unroll
    for (int m = 0; m < NPB; ++m){
        int p0 = row_ptr[n0 + m], p1 = row_ptr[n0 + m + 1];
        float s = 0.0f;
        for (int p = p0; p < p1; ++p){
            const float* pr = parts + (size_t)eidx[p] * H + o;
            #pragma unroll
            for (int sp = 0; sp < SPLITS; ++sp) s += pr[(size_t)sp * N_EDGES * H];
        }
        int d = p1 - p0;
        a[m] = s / (float)(d > 0 ? d : 1);
    }

    // root transform: one W read serves 4 nodes
    #pragma unroll 8
    for (int i = 0; i < H; ++i){
        float wv = W[i * H + o];
        #pragma unroll
        for (int m = 0; m < NPB; ++m) root[m] += hs[m][i] * wv;
    }

    float v[NPB];
    #pragma unroll
    for (int m = 0; m < NPB; ++m){
        float hn = fmaxf(a[m] + root[m], 0.0f);
        v[m] = hv[m] + hn;
        float s = v[m], q = v[m] * v[m];
        #pragma unroll
        for (int off = 32; off > 0; off >>= 1){
            s += __shfl_down(s, off, 64);
            q += __shfl_down(q, off, 64);
        }
        if ((o & 63) == 0){ red[m][0][o >> 6] = s; red[m][1][o >> 6] = q; }
    }
    __syncthreads();
    #pragma unroll
    for (int m = 0; m < NPB; ++m){
        float S = red[m][0][0] + red[m][0][1];
        float Q = red[m][1][0] + red[m][1][1];
        float mean = S * (1.0f / H);
        float var  = Q * (1.0f / H) - mean * mean;
        float out  = (v[m] - mean) * rsqrtf(var + 1e-5f) * lg[l * H + o] + lb[l * H + o];
        int n = n0 + m;
        h[(size_t)n * H + o]  = out;
        hb[(size_t)n * H + o] = f2b(out);
        if (dolast){
            int b = batch[n];
            atomicAdd(&molsum[b * H + o], out);
            if (o == 0) atomicAdd(&cnt[b], 1.0f);
        }
    }
}

// ---------- K7: head MLP ----------
__global__ void k_head(const float* __restrict__ molsum, const float* __restrict__ cnt,
                       const float* __restrict__ w1, const float* __restrict__ b1,
                       const float* __restrict__ w2, const float* __restrict__ b2,
                       float* __restrict__ out){
    __shared__ float mol[H];
    int g = blockIdx.x, t = threadIdx.x;   // 64 threads = 1 wave
    float c = fmaxf(cnt[g], 1.0f);
    mol[t]      = molsum[g * H + t] / c;
    mol[t + 64] = molsum[g * H + t + 64] / c;
    __syncthreads();
    float a = b1[t];
    #pragma unroll 8
    for (int i = 0; i < H; ++i) a += mol[i] * w1[i * 64 + t];
    float hid = gelu_exact(a);
    float p = hid * w2[t];
    #pragma unroll
    for (int off = 32; off > 0; off >>= 1) p += __shfl_down(p, off, 64);
    if (t == 0) out[g] = p + b2[0];
}

extern "C" void kernel_launch(void* const* d_in, const int* in_sizes, int n_in,
                              void* d_out, int out_size, void* d_ws, size_t ws_size,
                              hipStream_t stream){
    (void)in_sizes; (void)n_in; (void)out_size; (void)ws_size;
    const float* x     = (const float*)d_in[0];
    const int*   ei    = (const int*)  d_in[1];
    const float* ea    = (const float*)d_in[2];
    const int*   batch = (const int*)  d_in[3];
    const float* aw    = (const float*)d_in[4];
    const float* ab    = (const float*)d_in[5];
    const float* e1w   = (const float*)d_in[6];
    const float* e1b   = (const float*)d_in[7];
    const float* e2w   = (const float*)d_in[8];
    const float* e2b   = (const float*)d_in[9];
    const float* rw    = (const float*)d_in[10];
    const float* cb    = (const float*)d_in[11];
    const float* lg    = (const float*)d_in[12];
    const float* lb    = (const float*)d_in[13];
    const float* hw1   = (const float*)d_in[14];
    const float* hb1   = (const float*)d_in[15];
    const float* hw2   = (const float*)d_in[16];
    const float* hb2   = (const float*)d_in[17];
    float* out = (float*)d_out;

    char* p = (char*)d_ws;
    auto carve = [&](size_t bytes){ char* r = p; p += (bytes + 255) & ~(size_t)255; return r; };
    short* bt     = (short*)carve((size_t)NL * KS * SLICE_SH * 2);    // 12.7 MB
    float* h      = (float*)carve((size_t)N_NODES * H * 4);           // 2 MB
    short* hbuf   = (short*)carve((size_t)N_NODES * H * 2);           // 1 MB
    float* ehT    = (float*)carve((size_t)NL * KS * N_EDGES * 4);     // 12.7 MB
    float* parts  = (float*)carve((size_t)SPLITS * N_EDGES * H * 4);  // 16.7 MB
    int*   ideg   = (int*)  carve((size_t)N_NODES * 4);
    int*   row_ptr= (int*)  carve((size_t)(N_NODES + 1) * 4);
    int*   cursor = (int*)  carve((size_t)N_NODES * 4);
    int*   eidx   = (int*)  carve((size_t)N_EDGES * 4);
    float* molsum = (float*)carve((size_t)NGRAPH * H * 4);
    float* cnt    = (float*)carve((size_t)NGRAPH * 4);

    hipMemsetAsync(ideg, 0, (size_t)N_NODES * 4, stream);
    hipMemsetAsync(molsum, 0, (size_t)NGRAPH * H * 4, stream);
    hipMemsetAsync(cnt, 0, (size_t)NGRAPH * 4, stream);

    k_prep_b<<<NL * KS * 4, 256, 0, stream>>>(e2w, e2b, bt);
    k_atom<<<N_NODES, H, 0, stream>>>(x, aw, ab, h, hbuf);
    k_deg<<<N_EDGES / 256, 256, 0, stream>>>(ei, ideg);
    k_scan<<<1, 256, 0, stream>>>(ideg, row_ptr, cursor);
    k_fill<<<N_EDGES / 256, 256, 0, stream>>>(ei, cursor, eidx);
    k_edge_mlp<<<H * (N_EDGES / 256), 256, 0, stream>>>(ea, e1w, e1b, ehT);

    for (int l = 0; l < NL; ++l){
        k_msg_gemm<<<(N_EDGES / TILE_E) * 8, 256, 0, stream>>>(bt, ehT, hbuf, ei, parts, l);
        k_node<<<N_NODES / NPB, H, 0, stream>>>(parts, eidx, row_ptr, rw, cb, lg, lb,
                                                h, hbuf, batch, molsum, cnt, l,
                                                l == NL - 1 ? 1 : 0);
    }
    k_head<<<NGRAPH, 64, 0, stream>>>(molsum, cnt, hw1, hb1, hw2, hb2, out);
}